// Round 1
// baseline (856.931 us; speedup 1.0000x reference)
//
#include <hip/hip_runtime.h>

#define NLEVELS 16
#define TMASK 0xFFFFFu
#define PI2 2654435761u

// floor(16 * 1.26^l) for l=0..15, verified away from integer boundaries in fp32
__constant__ float c_NL[NLEVELS] = {
    16.f, 20.f, 25.f, 32.f, 40.f, 50.f, 64.f, 80.f,
    101.f, 128.f, 161.f, 203.f, 256.f, 322.f, 406.f, 512.f
};

__global__ __launch_bounds__(256) void hashgrid_kernel(
    const float2* __restrict__ x, const float* __restrict__ tb,
    float2* __restrict__ out, int npts)
{
    int tid = blockIdx.x * blockDim.x + threadIdx.x;
    int n = tid >> 4;
    int l = tid & 15;
    if (n >= npts) return;

    float2 xy = x[n];
    float nl = c_NL[l];
    float fx = xy.x * nl;
    float fy = xy.y * nl;
    int ixi = (int)fx;              // trunc == floor (x >= 0)
    int iyi = (int)fy;
    float lx = fx - (float)ixi;
    float ly = fy - (float)iyi;
    unsigned ix = (unsigned)ixi, iy = (unsigned)iyi;

    unsigned hy0 = iy * PI2;
    unsigned hy1 = (iy + 1u) * PI2;
    unsigned h0 = (ix        ^ hy0) & TMASK;
    unsigned h1 = ((ix + 1u) ^ hy0) & TMASK;
    unsigned h2 = (ix        ^ hy1) & TMASK;
    unsigned h3 = ((ix + 1u) ^ hy1) & TMASK;

    // hash_table layout [T, F=2, L=16]: entry (t, f, l) at t*32 + f*16 + l
    const float* p0 = tb + ((size_t)h0 * 32 + l);
    const float* p1 = tb + ((size_t)h1 * 32 + l);
    const float* p2 = tb + ((size_t)h2 * 32 + l);
    const float* p3 = tb + ((size_t)h3 * 32 + l);
    float a0 = p0[0], b0 = p0[16];
    float a1 = p1[0], b1 = p1[16];
    float a2 = p2[0], b2 = p2[16];
    float a3 = p3[0], b3 = p3[16];

    float w0 = (1.f - lx) * (1.f - ly);
    float w1 = lx * (1.f - ly);
    float w2 = (1.f - lx) * ly;
    float w3 = lx * ly;
    float o0 = w0 * a0 + w1 * a1 + w2 * a2 + w3 * a3;
    float o1 = w0 * b0 + w1 * b1 + w2 * b2 + w3 * b3;

    out[(size_t)n * NLEVELS + l] = make_float2(o0, o1);
}

extern "C" void kernel_launch(void* const* d_in, const int* in_sizes, int n_in,
                              void* d_out, int out_size, void* d_ws, size_t ws_size,
                              hipStream_t stream) {
    const float2* x = (const float2*)d_in[0];
    const float* tb = (const float*)d_in[1];
    float2* out = (float2*)d_out;
    int npts = in_sizes[0] / 2;           // x is [N, 2]
    long long total = (long long)npts * NLEVELS;
    int block = 256;
    long long grid = (total + block - 1) / block;
    hashgrid_kernel<<<(int)grid, block, 0, stream>>>(x, tb, out, npts);
}

// Round 2
// 547.795 us; speedup vs baseline: 1.5643x; 1.5643x over previous
//
#include <hip/hip_runtime.h>

#define NLEVELS 16
#define TSIZE (1u << 20)
#define TMASK 0xFFFFFu
#define PI2 2654435761u

// floor(16 * 1.26^l) for l=0..15, exact fp32 integers, away from boundaries
__constant__ float c_NL[NLEVELS] = {
    16.f, 20.f, 25.f, 32.f, 40.f, 50.f, 64.f, 80.f,
    101.f, 128.f, 161.f, 203.f, 256.f, 322.f, 406.f, 512.f
};

// ---- pass 1: transpose hash_table [T, F=2, L=16] -> ws [L][T] float2 ----
// block = 256 threads, 64 entries (8 KB) per block, LDS tile with +1 pad.
__global__ __launch_bounds__(256) void transpose_kernel(
    const float* __restrict__ tb, float2* __restrict__ ws)
{
    __shared__ float lds[64 * 33];
    int t0 = blockIdx.x * 64;
    int j = threadIdx.x;

    // load 64 entries * 32 floats = 512 float4, coalesced
    const float4* src = (const float4*)(tb + (size_t)t0 * 32);
    for (int g = j; g < 512; g += 256) {
        float4 v = src[g];
        int t = g >> 3;            // entry within tile
        int w = (g & 7) * 4;       // word within entry
        float* p = &lds[t * 33 + w];
        p[0] = v.x; p[1] = v.y; p[2] = v.z; p[3] = v.w;
    }
    __syncthreads();

    // thread j: level l = j>>4, entries tl..tl+3; write 32 B contiguous
    int l = j >> 4;
    int tl = (j & 15) * 4;
    float2 o[4];
    #pragma unroll
    for (int k = 0; k < 4; ++k) {
        o[k].x = lds[(tl + k) * 33 + l];        // f=0
        o[k].y = lds[(tl + k) * 33 + 16 + l];   // f=1
    }
    float4* d4 = (float4*)(ws + (size_t)l * TSIZE + t0 + tl);
    d4[0] = make_float4(o[0].x, o[0].y, o[1].x, o[1].y);
    d4[1] = make_float4(o[2].x, o[2].y, o[3].x, o[3].y);
}

// ---- pass 2: encode, one thread per (point, level) ----
__global__ __launch_bounds__(256) void hashgrid2_kernel(
    const float2* __restrict__ x, const float2* __restrict__ ws,
    float2* __restrict__ out, int npts)
{
    int tid = blockIdx.x * blockDim.x + threadIdx.x;
    int n = tid >> 4;
    int l = tid & 15;
    if (n >= npts) return;

    float2 xy = x[n];
    float nl = c_NL[l];
    float fx = xy.x * nl;
    float fy = xy.y * nl;
    int ixi = (int)fx;
    int iyi = (int)fy;
    float lx = fx - (float)ixi;
    float ly = fy - (float)iyi;
    unsigned ix = (unsigned)ixi, iy = (unsigned)iyi;

    unsigned hy0 = iy * PI2;
    unsigned hy1 = (iy + 1u) * PI2;
    unsigned h0 = (ix        ^ hy0) & TMASK;
    unsigned h1 = ((ix + 1u) ^ hy0) & TMASK;
    unsigned h2 = (ix        ^ hy1) & TMASK;
    unsigned h3 = ((ix + 1u) ^ hy1) & TMASK;

    const float2* lt = ws + (size_t)l * TSIZE;
    float2 H0 = lt[h0];
    float2 H1 = lt[h1];
    float2 H2 = lt[h2];
    float2 H3 = lt[h3];

    float w0 = (1.f - lx) * (1.f - ly);
    float w1 = lx * (1.f - ly);
    float w2 = (1.f - lx) * ly;
    float w3 = lx * ly;
    float o0 = w0 * H0.x + w1 * H1.x + w2 * H2.x + w3 * H3.x;
    float o1 = w0 * H0.y + w1 * H1.y + w2 * H2.y + w3 * H3.y;

    out[(size_t)n * NLEVELS + l] = make_float2(o0, o1);
}

// ---- fallback (round-1 kernel) if ws is too small ----
__global__ __launch_bounds__(256) void hashgrid_kernel(
    const float2* __restrict__ x, const float* __restrict__ tb,
    float2* __restrict__ out, int npts)
{
    int tid = blockIdx.x * blockDim.x + threadIdx.x;
    int n = tid >> 4;
    int l = tid & 15;
    if (n >= npts) return;

    float2 xy = x[n];
    float nl = c_NL[l];
    float fx = xy.x * nl;
    float fy = xy.y * nl;
    int ixi = (int)fx;
    int iyi = (int)fy;
    float lx = fx - (float)ixi;
    float ly = fy - (float)iyi;
    unsigned ix = (unsigned)ixi, iy = (unsigned)iyi;

    unsigned hy0 = iy * PI2;
    unsigned hy1 = (iy + 1u) * PI2;
    unsigned h0 = (ix        ^ hy0) & TMASK;
    unsigned h1 = ((ix + 1u) ^ hy0) & TMASK;
    unsigned h2 = (ix        ^ hy1) & TMASK;
    unsigned h3 = ((ix + 1u) ^ hy1) & TMASK;

    const float* p0 = tb + ((size_t)h0 * 32 + l);
    const float* p1 = tb + ((size_t)h1 * 32 + l);
    const float* p2 = tb + ((size_t)h2 * 32 + l);
    const float* p3 = tb + ((size_t)h3 * 32 + l);
    float a0 = p0[0], b0 = p0[16];
    float a1 = p1[0], b1 = p1[16];
    float a2 = p2[0], b2 = p2[16];
    float a3 = p3[0], b3 = p3[16];

    float w0 = (1.f - lx) * (1.f - ly);
    float w1 = lx * (1.f - ly);
    float w2 = (1.f - lx) * ly;
    float w3 = lx * ly;
    float o0 = w0 * a0 + w1 * a1 + w2 * a2 + w3 * a3;
    float o1 = w0 * b0 + w1 * b1 + w2 * b2 + w3 * b3;

    out[(size_t)n * NLEVELS + l] = make_float2(o0, o1);
}

extern "C" void kernel_launch(void* const* d_in, const int* in_sizes, int n_in,
                              void* d_out, int out_size, void* d_ws, size_t ws_size,
                              hipStream_t stream) {
    const float2* x = (const float2*)d_in[0];
    const float* tb = (const float*)d_in[1];
    float2* out = (float2*)d_out;
    int npts = in_sizes[0] / 2;
    long long total = (long long)npts * NLEVELS;
    int block = 256;
    long long grid = (total + block - 1) / block;

    size_t need = (size_t)NLEVELS * TSIZE * sizeof(float2);   // 128 MiB
    if (ws_size >= need) {
        float2* ws = (float2*)d_ws;
        transpose_kernel<<<TSIZE / 64, 256, 0, stream>>>(tb, ws);
        hashgrid2_kernel<<<(int)grid, block, 0, stream>>>(x, ws, out, npts);
    } else {
        hashgrid_kernel<<<(int)grid, block, 0, stream>>>(x, tb, out, npts);
    }
}

// Round 3
// 475.610 us; speedup vs baseline: 1.8018x; 1.1518x over previous
//
#include <hip/hip_runtime.h>

#define NLEVELS 16
#define TSIZE (1u << 20)
#define TMASK 0xFFFFFu
#define PI2 2654435761u

// floor(16 * 1.26^l) for l=0..15, exact fp32 integers, away from boundaries
__constant__ float c_NL[NLEVELS] = {
    16.f, 20.f, 25.f, 32.f, 40.f, 50.f, 64.f, 80.f,
    101.f, 128.f, 161.f, 203.f, 256.f, 322.f, 406.f, 512.f
};

// ---- pass 1: transpose hash_table [T, F=2, L=16] -> ws [L][T] float2 ----
__global__ __launch_bounds__(256) void transpose_kernel(
    const float* __restrict__ tb, float2* __restrict__ ws)
{
    __shared__ float lds[64 * 33];
    int t0 = blockIdx.x * 64;
    int j = threadIdx.x;

    const float4* src = (const float4*)(tb + (size_t)t0 * 32);
    for (int g = j; g < 512; g += 256) {
        float4 v = src[g];
        int t = g >> 3;
        int w = (g & 7) * 4;
        float* p = &lds[t * 33 + w];
        p[0] = v.x; p[1] = v.y; p[2] = v.z; p[3] = v.w;
    }
    __syncthreads();

    int l = j >> 4;
    int tl = (j & 15) * 4;
    float2 o[4];
    #pragma unroll
    for (int k = 0; k < 4; ++k) {
        o[k].x = lds[(tl + k) * 33 + l];
        o[k].y = lds[(tl + k) * 33 + 16 + l];
    }
    float4* d4 = (float4*)(ws + (size_t)l * TSIZE + t0 + tl);
    d4[0] = make_float4(o[0].x, o[0].y, o[1].x, o[1].y);
    d4[1] = make_float4(o[2].x, o[2].y, o[3].x, o[3].y);
}

// ---- pass 2: one thread = one point x 8 levels; 32 gathers in flight ----
__global__ __launch_bounds__(256) void hashgrid8_kernel(
    const float2* __restrict__ x, const float2* __restrict__ ws,
    float2* __restrict__ out, int npts, int nchunks)
{
    int bid = blockIdx.x;
    int g = (bid >= nchunks) ? 1 : 0;          // group-major: levels 8g..8g+7
    int chunk = bid - g * nchunks;
    int n = chunk * 256 + threadIdx.x;
    if (n >= npts) return;
    int lbase = g * 8;

    float2 xy = x[n];

    float2 H[8][4];
    float lxv[8], lyv[8];
    #pragma unroll
    for (int k = 0; k < 8; ++k) {
        float nl = c_NL[lbase + k];
        float fx = xy.x * nl;
        float fy = xy.y * nl;
        int ixi = (int)fx;                     // trunc == floor (x >= 0)
        int iyi = (int)fy;
        lxv[k] = fx - (float)ixi;
        lyv[k] = fy - (float)iyi;
        unsigned ix = (unsigned)ixi, iy = (unsigned)iyi;
        unsigned hy0 = iy * PI2;
        unsigned hy1 = (iy + 1u) * PI2;
        const float2* lt = ws + (size_t)(lbase + k) * TSIZE;
        H[k][0] = lt[(ix        ^ hy0) & TMASK];
        H[k][1] = lt[((ix + 1u) ^ hy0) & TMASK];
        H[k][2] = lt[(ix        ^ hy1) & TMASK];
        H[k][3] = lt[((ix + 1u) ^ hy1) & TMASK];
    }

    float2 r[8];
    #pragma unroll
    for (int k = 0; k < 8; ++k) {
        float lx = lxv[k], ly = lyv[k];
        float w0 = (1.f - lx) * (1.f - ly);
        float w1 = lx * (1.f - ly);
        float w2 = (1.f - lx) * ly;
        float w3 = lx * ly;
        r[k].x = w0*H[k][0].x + w1*H[k][1].x + w2*H[k][2].x + w3*H[k][3].x;
        r[k].y = w0*H[k][0].y + w1*H[k][1].y + w2*H[k][2].y + w3*H[k][3].y;
    }

    // 64 B contiguous per thread: one full cache line, no partial-line RMW
    float4* dst = (float4*)(out + (size_t)n * NLEVELS + lbase);
    #pragma unroll
    for (int k = 0; k < 4; ++k)
        dst[k] = make_float4(r[2*k].x, r[2*k].y, r[2*k+1].x, r[2*k+1].y);
}

// ---- fallback (round-1 kernel) if ws is too small ----
__global__ __launch_bounds__(256) void hashgrid_kernel(
    const float2* __restrict__ x, const float* __restrict__ tb,
    float2* __restrict__ out, int npts)
{
    int tid = blockIdx.x * blockDim.x + threadIdx.x;
    int n = tid >> 4;
    int l = tid & 15;
    if (n >= npts) return;

    float2 xy = x[n];
    float nl = c_NL[l];
    float fx = xy.x * nl;
    float fy = xy.y * nl;
    int ixi = (int)fx;
    int iyi = (int)fy;
    float lx = fx - (float)ixi;
    float ly = fy - (float)iyi;
    unsigned ix = (unsigned)ixi, iy = (unsigned)iyi;

    unsigned hy0 = iy * PI2;
    unsigned hy1 = (iy + 1u) * PI2;
    unsigned h0 = (ix        ^ hy0) & TMASK;
    unsigned h1 = ((ix + 1u) ^ hy0) & TMASK;
    unsigned h2 = (ix        ^ hy1) & TMASK;
    unsigned h3 = ((ix + 1u) ^ hy1) & TMASK;

    const float* p0 = tb + ((size_t)h0 * 32 + l);
    const float* p1 = tb + ((size_t)h1 * 32 + l);
    const float* p2 = tb + ((size_t)h2 * 32 + l);
    const float* p3 = tb + ((size_t)h3 * 32 + l);
    float a0 = p0[0], b0 = p0[16];
    float a1 = p1[0], b1 = p1[16];
    float a2 = p2[0], b2 = p2[16];
    float a3 = p3[0], b3 = p3[16];

    float w0 = (1.f - lx) * (1.f - ly);
    float w1 = lx * (1.f - ly);
    float w2 = (1.f - lx) * ly;
    float w3 = lx * ly;
    float o0 = w0 * a0 + w1 * a1 + w2 * a2 + w3 * a3;
    float o1 = w0 * b0 + w1 * b1 + w2 * b2 + w3 * b3;

    out[(size_t)n * NLEVELS + l] = make_float2(o0, o1);
}

extern "C" void kernel_launch(void* const* d_in, const int* in_sizes, int n_in,
                              void* d_out, int out_size, void* d_ws, size_t ws_size,
                              hipStream_t stream) {
    const float2* x = (const float2*)d_in[0];
    const float* tb = (const float*)d_in[1];
    float2* out = (float2*)d_out;
    int npts = in_sizes[0] / 2;

    size_t need = (size_t)NLEVELS * TSIZE * sizeof(float2);   // 128 MiB
    if (ws_size >= need) {
        float2* ws = (float2*)d_ws;
        transpose_kernel<<<TSIZE / 64, 256, 0, stream>>>(tb, ws);
        int nchunks = (npts + 255) / 256;
        hashgrid8_kernel<<<2 * nchunks, 256, 0, stream>>>(x, ws, out, npts, nchunks);
    } else {
        long long total = (long long)npts * NLEVELS;
        long long grid = (total + 255) / 256;
        hashgrid_kernel<<<(int)grid, 256, 0, stream>>>(x, tb, out, npts);
    }
}